// Round 2
// baseline (729.141 us; speedup 1.0000x reference)
//
#include <hip/hip_runtime.h>
#include <cstdint>
#include <cstddef>

// ---------------- problem constants ----------------
#define L_SEQ   4096
#define DIM_IN  1024
#define DI      1536
#define BATCH   4

typedef unsigned short u16;
typedef __attribute__((ext_vector_type(8))) short  short8;   // 8 bf16 = 4 VGPRs
typedef __attribute__((ext_vector_type(4))) float  f32x4;

struct __align__(8) u16x4 { u16 x, y, z, w; };

// ---------------- helpers ----------------
__device__ __forceinline__ float bf2f(u16 u) {
  union { unsigned int i; float f; } v; v.i = ((unsigned int)u) << 16; return v.f;
}
__device__ __forceinline__ u16 f2bf(float f) {
  union { float f; unsigned int i; } v; v.f = f;
  unsigned int x = v.i;
  return (u16)((x + 0x7fffu + ((x >> 16) & 1u)) >> 16);   // RNE
}
__device__ __forceinline__ float siluf_(float v) {
  return v / (1.0f + __expf(-v));
}
__device__ __forceinline__ float softplusf_(float v) {
  return fmaxf(v, 0.0f) + log1pf(__expf(-fabsf(v)));
}
__device__ __forceinline__ void gload16(const void* g, void* l) {
  __builtin_amdgcn_global_load_lds((const __attribute__((address_space(1))) void*)g,
                                   (__attribute__((address_space(3))) void*)l,
                                   16, 0, 0);
}
// LDS byte offset of a generic pointer into __shared__ (addrspacecast strips aperture)
__device__ __forceinline__ unsigned lds_off(const void* p) {
  return (unsigned)(uintptr_t)(const __attribute__((address_space(3))) void*)p;
}
// inline-asm ds_read_b128: invisible to the waitcnt pass (no conservative vmcnt(0)
// before LDS reads that alias outstanding global_load_lds DMA). Caller MUST pair
// with s_waitcnt lgkmcnt(0) + sched_barrier(0) before consuming (rule #18).
__device__ __forceinline__ short8 dsread128(unsigned off) {
  short8 r;
  asm volatile("ds_read_b128 %0, %1" : "=v"(r) : "v"(off));
  return r;
}

// ---------------- fp32 -> bf16 convert ----------------
__global__ void to_bf16(const float* __restrict__ in, u16* __restrict__ out, int n4) {
  int i = blockIdx.x * blockDim.x + threadIdx.x;
  if (i >= n4) return;
  float4 v = ((const float4*)in)[i];
  u16x4 o;
  o.x = f2bf(v.x); o.y = f2bf(v.y); o.z = f2bf(v.z); o.w = f2bf(v.w);
  ((u16x4*)out)[i] = o;
}

// ---------------- 256x256 8-phase bf16 MFMA GEMM, C = A(MxK) * Bt(NxK)^T ------
// m201-style: BM=BN=256, BK=64, 8 waves (4M x 2N), per-wave 64x128, 128 KiB LDS
// double-buffered, XOR-swizzle (elem ^= (row&7)<<3) via pre-swizzled global src +
// swizzled asm ds_read. Counted vmcnt(6) once per K-tile (never 0 in the loop).
// All LDS fragment reads are inline-asm ds_read_b128 so LLVM's waitcnt pass cannot
// insert per-phase vmcnt(0) drains (round-1 failure mode: MfmaUtil 11.6%).
//
// vmcnt ledger (1 gload16 issue = 1 vmem op; 2 per STAGE_*):
//   prologue: tile0 (8 issues) + A0,A1,B0 of tile1 (6) -> vmcnt(6) = tile0 landed.
//   iter t: P0 +B1(t+1) [8 out]; P1 +A0(t+2) [10]; P2 +A1(t+2) [12]; P3 +B0(t+2)
//   [14] -> vmcnt(6) drains the 8 oldest = all of tile t+1. Steady state 6 in flight.
// Same-buffer staging (t+2 -> cur) is race-free: A[cur] rewritten only after P0's
// a-reads (barrier-separated); B0-stage rows disjoint from P3's reads; tail clamp
// re-issues identical bytes (benign).

__device__ __forceinline__ void mma_ph(f32x4 (&acc)[4][8], const short8 (&a)[4][2],
                                       const short8 (&b)[2][2], int p) {
  // kb-outer: 8 independent acc slots per sweep, dependent pair 8 instrs apart
#pragma unroll
  for (int kb = 0; kb < 2; ++kb)
#pragma unroll
    for (int i = 0; i < 4; ++i)
#pragma unroll
      for (int n = 0; n < 2; ++n)
        acc[i][p * 2 + n] = __builtin_amdgcn_mfma_f32_16x16x32_bf16(a[i][kb], b[n][kb],
                                                                    acc[i][p * 2 + n], 0, 0, 0);
}

// EPI 0: plain fp32 C store (c_out, ld N)
// EPI 1: in_proj split: col<DI -> bf16 e_bf_a ; col>=DI -> silu -> bf16 e_bf1
// EPI 2: dt epilogue: dt=softplus(acc+e_v2[col]); a=exp(e_v1[col]*dt);
//        w = bf2f(e_bf2[row,col])*dt*a -> e_bf_a ; a -> e_bf1
template <int EPI>
__launch_bounds__(512, 2)
__global__ void gemm256(const u16* __restrict__ A, const u16* __restrict__ Bt,
                        float* __restrict__ c_out,
                        int N, int K,
                        u16* __restrict__ e_bf_a,
                        u16* __restrict__ e_bf1,
                        const u16* __restrict__ e_bf2,
                        const float* __restrict__ e_v1,
                        const float* __restrict__ e_v2) {
  __shared__ u16 smem[2][2][256 * 64];   // 128 KiB: [dbuf][A|B][256r][64c]

  const int tid  = threadIdx.x;          // 0..511
  const int wave = tid >> 6;             // 0..7
  const int lane = tid & 63;
  const int quad = lane >> 4;
  const int l16  = lane & 15;
  const int waveM = wave & 3;            // 4 M-groups of 64 rows
  const int waveN = wave >> 2;           // 2 N-groups of 128 cols
  const int xorc  = (l16 & 7) << 3;      // LDS read swizzle (elements)

  // bijective XCD-aware block swizzle (all grids here are multiples of 8 WGs)
  const int nwg  = (int)(gridDim.x * gridDim.y);
  const int orig = (int)(blockIdx.y * gridDim.x + blockIdx.x);
  const int swz  = (orig & 7) * (nwg >> 3) + (orig >> 3);
  const int bx   = swz % (int)gridDim.x;
  const int by   = swz / (int)gridDim.x;
  const int m0 = by * 256;
  const int n0 = bx * 256;
  const int NT = K >> 6;                 // K-tiles of 64

  // staging: thread t covers (row = t>>3, 16B seg = t&7); source col pre-swizzled
  // so linear global_load_lds lands the swizzled layout (both-sides involution).
  const int srow = tid >> 3;
  const int scol = ((tid & 7) ^ (srow & 7)) * 8;
  const u16* gA = A  + (size_t)(m0 + srow) * K + scol;
  const u16* gB = Bt + (size_t)(n0 + srow) * K + scol;

#define STAGE2(gptr, mat, kk, r0, r1) do {                                      \
    const u16* _s0 = gptr + (size_t)(r0) * K + (size_t)(kk) * 64;               \
    const u16* _s1 = gptr + (size_t)(r1) * K + (size_t)(kk) * 64;               \
    gload16(_s0, &smem[(kk) & 1][mat][((r0) + wave * 8) * 64]);                 \
    gload16(_s1, &smem[(kk) & 1][mat][((r1) + wave * 8) * 64]);                 \
  } while (0)
#define STAGE_A(kk, h) STAGE2(gA, 0, kk, (h) * 128, (h) * 128 + 64)
#define STAGE_B(kk, h) STAGE2(gB, 1, kk, (h) * 64, (h) * 64 + 128)

  {
    const int p1 = NT > 1 ? 1 : 0;
    STAGE_A(0, 0); STAGE_A(0, 1); STAGE_B(0, 0); STAGE_B(0, 1);
    STAGE_A(p1, 0); STAGE_A(p1, 1); STAGE_B(p1, 0);
  }
  asm volatile("s_waitcnt vmcnt(6)" ::: "memory");
  __builtin_amdgcn_s_barrier();

  f32x4 acc[4][8] = {};
  short8 a[4][2], b[2][2];

  // hoisted LDS addressing (bytes): row stride 128 B, 16-row block 2048 B
  const unsigned ldsBase = lds_off(&smem[0][0][0]);
  const unsigned rowA = (unsigned)(waveM * 64 + l16) * 128u;   // wave's A row base
  const unsigned rowB = (unsigned)(waveN * 128 + l16) * 128u;  // wave's B row base
  const unsigned ck0  = (unsigned)(((0 * 32 + quad * 8) ^ xorc) * 2);
  const unsigned ck1  = (unsigned)(((1 * 32 + quad * 8) ^ xorc) * 2);

#define LDB(Bc, p) do {                                                         \
    const unsigned _rb = (Bc) + rowB + (unsigned)(p) * 4096u;                   \
    b[0][0] = dsread128(_rb + ck0);                                             \
    b[0][1] = dsread128(_rb + ck1);                                             \
    b[1][0] = dsread128(_rb + 2048u + ck0);                                     \
    b[1][1] = dsread128(_rb + 2048u + ck1);                                     \
  } while (0)

#define WAIT_LGKM() do {                                                        \
    asm volatile("s_waitcnt lgkmcnt(0)" ::: "memory");                          \
    __builtin_amdgcn_sched_barrier(0);                                          \
  } while (0)

  for (int t = 0; t < NT; ++t) {
    const int cur = t & 1;
    const int k1  = (t + 1 < NT) ? t + 1 : NT - 1;
    const int k2  = (t + 2 < NT) ? t + 2 : NT - 1;
    const unsigned Ac = ldsBase + (unsigned)cur * 65536u;
    const unsigned Bc = Ac + 32768u;

    // ---- phase 0: asm ds_read A(all) + B p=0 ; stage B1(k1) ; MFMA p=0
#pragma unroll
    for (int i = 0; i < 4; ++i) {
      const unsigned ra = Ac + rowA + (unsigned)i * 2048u;
      a[i][0] = dsread128(ra + ck0);
      a[i][1] = dsread128(ra + ck1);
    }
    LDB(Bc, 0);
    STAGE_B(k1, 1);
    __builtin_amdgcn_s_barrier();
    WAIT_LGKM();
    __builtin_amdgcn_s_setprio(1);
    mma_ph(acc, a, b, 0);
    __builtin_amdgcn_s_setprio(0);
    __builtin_amdgcn_s_barrier();

    // ---- phase 1: B p=1 ; stage A0(k2) ; MFMA p=1
    LDB(Bc, 1);
    STAGE_A(k2, 0);
    __builtin_amdgcn_s_barrier();
    WAIT_LGKM();
    __builtin_amdgcn_s_setprio(1);
    mma_ph(acc, a, b, 1);
    __builtin_amdgcn_s_setprio(0);
    __builtin_amdgcn_s_barrier();

    // ---- phase 2: B p=2 ; stage A1(k2) ; MFMA p=2
    LDB(Bc, 2);
    STAGE_A(k2, 1);
    __builtin_amdgcn_s_barrier();
    WAIT_LGKM();
    __builtin_amdgcn_s_setprio(1);
    mma_ph(acc, a, b, 2);
    __builtin_amdgcn_s_setprio(0);
    __builtin_amdgcn_s_barrier();

    // ---- phase 3: B p=3 ; stage B0(k2) ; vmcnt(6) counted (never 0) ; MFMA p=3
    LDB(Bc, 3);
    STAGE_B(k2, 0);
    asm volatile("s_waitcnt vmcnt(6)" ::: "memory");
    __builtin_amdgcn_s_barrier();
    WAIT_LGKM();
    __builtin_amdgcn_s_setprio(1);
    mma_ph(acc, a, b, 3);
    __builtin_amdgcn_s_setprio(0);
    __builtin_amdgcn_s_barrier();
  }
#undef STAGE_A
#undef STAGE_B
#undef STAGE2
#undef LDB
#undef WAIT_LGKM

  // epilogue: C/D layout col=lane&15, row=quad*4+reg (m89/m91-verified)
#pragma unroll
  for (int mi = 0; mi < 4; ++mi) {
    const int rowBase = m0 + waveM * 64 + mi * 16 + quad * 4;
#pragma unroll
    for (int ni = 0; ni < 8; ++ni) {
      const int gcol = n0 + waveN * 128 + ni * 16 + l16;
#pragma unroll
      for (int r = 0; r < 4; ++r) {
        const float v = acc[mi][ni][r];
        const size_t row = (size_t)(rowBase + r);
        if constexpr (EPI == 0) {
          c_out[row * (size_t)N + gcol] = v;
        } else if constexpr (EPI == 1) {
          if (gcol < DI) {
            e_bf_a[row * DI + gcol] = f2bf(v);
          } else {
            e_bf1[row * DI + (gcol - DI)] = f2bf(siluf_(v));
          }
        } else {
          const float dt = softplusf_(v + e_v2[gcol]);
          const float aa = __expf(e_v1[gcol] * dt);
          const float xc = bf2f(e_bf2[row * DI + gcol]);
          e_bf_a[row * DI + gcol] = f2bf(xc * dt * aa);
          e_bf1[row * DI + gcol]  = f2bf(aa);
        }
      }
    }
  }
}

// ---------------- depthwise conv1d(k=3,pad=1) + bias + SiLU ----------------------
__global__ void conv_silu(const u16* __restrict__ xin, const float* __restrict__ cw,
                          const float* __restrict__ cb, u16* __restrict__ xconv_bf) {
  const int idx = blockIdx.x * blockDim.x + threadIdx.x;   // one thread = 4 channels
  const int c4  = (idx % (DI / 4)) * 4;
  const int row = idx / (DI / 4);
  const int l   = row & (L_SEQ - 1);

  const size_t base = (size_t)row * DI + c4;
  u16x4 z4 = {0, 0, 0, 0};
  u16x4 x1 = *(const u16x4*)(xin + base);
  u16x4 x0 = (l > 0)         ? *(const u16x4*)(xin + base - DI) : z4;
  u16x4 x2 = (l < L_SEQ - 1) ? *(const u16x4*)(xin + base + DI) : z4;

  const u16* p0 = (const u16*)&x0;
  const u16* p1 = (const u16*)&x1;
  const u16* p2 = (const u16*)&x2;
  u16x4 o;
  u16* po = (u16*)&o;
#pragma unroll
  for (int j = 0; j < 4; j++) {
    const int c = c4 + j;
    float v = fmaf(cw[c * 3 + 0], bf2f(p0[j]),
              fmaf(cw[c * 3 + 1], bf2f(p1[j]),
                   cw[c * 3 + 2] * bf2f(p2[j]))) + cb[c];
    po[j] = f2bf(siluf_(v));
  }
  *(u16x4*)&xconv_bf[base] = o;
}

// ---------------- chunked prefix scan over L (chunk=128, 32 chunks/batch) --------
#define CHUNK 128
#define NCHUNK (L_SEQ / CHUNK)   // 32

__global__ void scan_partial(const u16* __restrict__ w, float* __restrict__ partial) {
  const int c  = blockIdx.x * 256 + threadIdx.x;   // 0..1535
  const int ch = blockIdx.y;
  const int b  = blockIdx.z;
  size_t base = ((size_t)b * L_SEQ + (size_t)ch * CHUNK) * DI + c;
  float s = 0.0f;
#pragma unroll 4
  for (int i = 0; i < CHUNK; i++) s += bf2f(w[base + (size_t)i * DI]);
  partial[((size_t)b * NCHUNK + ch) * DI + c] = s;
}

__global__ void scan_offsets(float* __restrict__ partial) {
  const int c = blockIdx.x * 256 + threadIdx.x;    // 0..1535
  const int b = blockIdx.z;
  float run = 0.0f;
  for (int ch = 0; ch < NCHUNK; ch++) {
    size_t p = ((size_t)b * NCHUNK + ch) * DI + c;
    float v = partial[p];
    partial[p] = run;
    run += v;
  }
}

// NOTE: ybf aliases aexp (same index read-then-write per thread) — no __restrict__.
__global__ void scan_apply(const u16* __restrict__ w, const float* __restrict__ partial,
                           const u16* aexp, const u16* __restrict__ xconv,
                           const u16* __restrict__ sz, const float* __restrict__ Dp,
                           u16* ybf) {
  const int c  = blockIdx.x * 256 + threadIdx.x;
  const int ch = blockIdx.y;
  const int b  = blockIdx.z;
  float run = partial[((size_t)b * NCHUNK + ch) * DI + c];
  const float dp = Dp[c];
  size_t base = ((size_t)b * L_SEQ + (size_t)ch * CHUNK) * DI + c;
  for (int i = 0; i < CHUNK; i++) {
    size_t p = base + (size_t)i * DI;
    float ae = bf2f(aexp[p]);             // read BEFORE the aliased write
    run += bf2f(w[p]);
    float y = run * ae + bf2f(xconv[p]) * dp;
    y *= bf2f(sz[p]);
    ybf[p] = f2bf(y);
  }
}

// ---------------- launcher ----------------
extern "C" void kernel_launch(void* const* d_in, const int* in_sizes, int n_in,
                              void* d_out, int out_size, void* d_ws, size_t ws_size,
                              hipStream_t stream) {
  const float* x      = (const float*)d_in[0];
  const float* W_in   = (const float*)d_in[1];   // (3072,1024)
  const float* W_out  = (const float*)d_in[2];   // (1024,1536)
  const float* conv_w = (const float*)d_in[3];   // (1536,1,3)
  const float* conv_b = (const float*)d_in[4];
  const float* dt_w   = (const float*)d_in[5];   // (1536,1536)
  const float* dt_b   = (const float*)d_in[6];
  const float* Avec   = (const float*)d_in[7];
  const float* Dp     = (const float*)d_in[8];
  float* out = (float*)d_out;
  char* ws = (char*)d_ws;

  // weights -> bf16 (shared by both paths; layout prefix identical)
  u16* Win_bf  = (u16*)(ws + 0);          //  6,291,456
  u16* dtw_bf  = (u16*)(ws + 6291456);    //  4,718,592
  u16* Wout_bf = (u16*)(ws + 11010048);   //  3,145,728  -> end 14,155,776
  to_bf16<<<3072, 256, 0, stream>>>(W_in,  Win_bf,  786432);
  to_bf16<<<2304, 256, 0, stream>>>(dt_w,  dtw_bf,  589824);
  to_bf16<<<1536, 256, 0, stream>>>(W_out, Wout_bf, 393216);

  const size_t FULL_NEED = 249823232;   // full-batch layout
  if (ws_size >= FULL_NEED) {
    // ---------- full-batch path: M = 16384 ----------
    u16*   x_bf     = (u16*)  (ws + 14155776);    // 33,554,432  (16384x1024)
    u16*   xin_bf   = (u16*)  (ws + 47710208);    // 50,331,648  [w aliases]
    u16*   sz_bf    = (u16*)  (ws + 98041856);    // 50,331,648
    u16*   xconv_bf = (u16*)  (ws + 148373504);   // 50,331,648
    u16*   aexp_bf  = (u16*)  (ws + 198705152);   // 50,331,648  [y aliases]
    float* part     = (float*)(ws + 249036800);   //    786,432  (4x32x1536)
    u16*   w_bf     = xin_bf;
    u16*   y_bf     = aexp_bf;

    to_bf16<<<16384, 256, 0, stream>>>(x, x_bf, 4194304);

    // in_proj GEMM (M=16384, N=3072, K=1024) + split epilogue
    gemm256<1><<<dim3(12, 64), 512, 0, stream>>>(x_bf, Win_bf, nullptr,
                                                 2 * DI, DIM_IN,
                                                 xin_bf, sz_bf, nullptr, nullptr, nullptr);
    // depthwise conv + SiLU (batch edges via l = row & 4095)
    conv_silu<<<24576, 256, 0, stream>>>(xin_bf, conv_w, conv_b, xconv_bf);

    // dt GEMM (M=16384, N=1536, K=1536) + softplus/exp/w epilogue
    gemm256<2><<<dim3(6, 64), 512, 0, stream>>>(xconv_bf, dtw_bf, nullptr,
                                                DI, DI,
                                                w_bf, aexp_bf, xconv_bf, Avec, dt_b);

    // chunked prefix scan + pointwise tail
    scan_partial<<<dim3(6, NCHUNK, BATCH), 256, 0, stream>>>(w_bf, part);
    scan_offsets<<<dim3(6, 1, BATCH), 256, 0, stream>>>(part);
    scan_apply<<<dim3(6, NCHUNK, BATCH), 256, 0, stream>>>(w_bf, part, aexp_bf,
                                                           xconv_bf, sz_bf, Dp, y_bf);

    // out_proj GEMM (M=16384, N=1024, K=1536) -> fp32 output
    gemm256<0><<<dim3(4, 64), 512, 0, stream>>>(y_bf, Wout_bf, out,
                                                DIM_IN, DI,
                                                nullptr, nullptr, nullptr, nullptr, nullptr);
    return;
  }

  // ---------- per-batch fallback (73 MB), M = 4096 ----------
  const size_t WS_NEED = 73072640;
  if (ws_size < WS_NEED) return;   // diagnostic: absmax=2096 w/o crash => ws too small

  u16*   x_bf     = (u16*)  (ws + 14155776);   //  8,388,608   (4096x1024)
  u16*   xin_bf   = (u16*)  (ws + 22544384);   // 12,582,912   [w aliases]
  u16*   sz_bf    = (u16*)  (ws + 35127296);   // 12,582,912
  u16*   xconv_bf = (u16*)  (ws + 47710208);   // 12,582,912
  u16*   aexp_bf  = (u16*)  (ws + 60293120);   // 12,582,912   [y aliases]
  float* part     = (float*)(ws + 72876032);   //    196,608
  u16*   w_bf     = xin_bf;
  u16*   y_bf     = aexp_bf;

  for (int b = 0; b < BATCH; b++) {
    const float* xb   = x   + (size_t)b * L_SEQ * DIM_IN;
    float*       outb = out + (size_t)b * L_SEQ * DIM_IN;

    to_bf16<<<4096, 256, 0, stream>>>(xb, x_bf, 1048576);
    gemm256<1><<<dim3(12, 16), 512, 0, stream>>>(x_bf, Win_bf, nullptr,
                                                 2 * DI, DIM_IN,
                                                 xin_bf, sz_bf, nullptr, nullptr, nullptr);
    conv_silu<<<6144, 256, 0, stream>>>(xin_bf, conv_w, conv_b, xconv_bf);
    gemm256<2><<<dim3(6, 16), 512, 0, stream>>>(xconv_bf, dtw_bf, nullptr,
                                                DI, DI,
                                                w_bf, aexp_bf, xconv_bf, Avec, dt_b);
    scan_partial<<<dim3(6, NCHUNK, 1), 256, 0, stream>>>(w_bf, part);
    scan_offsets<<<dim3(6, 1, 1), 256, 0, stream>>>(part);
    scan_apply<<<dim3(6, NCHUNK, 1), 256, 0, stream>>>(w_bf, part, aexp_bf,
                                                       xconv_bf, sz_bf, Dp, y_bf);
    gemm256<0><<<dim3(4, 16), 512, 0, stream>>>(y_bf, Wout_bf, outb,
                                                DIM_IN, DI,
                                                nullptr, nullptr, nullptr, nullptr, nullptr);
  }
}

// Round 3
// 567.007 us; speedup vs baseline: 1.2859x; 1.2859x over previous
//
#include <hip/hip_runtime.h>
#include <cstdint>
#include <cstddef>

// ---------------- problem constants ----------------
#define L_SEQ   4096
#define DIM_IN  1024
#define DI      1536
#define BATCH   4

typedef unsigned short u16;
typedef __attribute__((ext_vector_type(8))) short  short8;   // 8 bf16 = 4 VGPRs
typedef __attribute__((ext_vector_type(4))) float  f32x4;

struct __align__(8) u16x4 { u16 x, y, z, w; };

// ---------------- helpers ----------------
__device__ __forceinline__ float bf2f(u16 u) {
  union { unsigned int i; float f; } v; v.i = ((unsigned int)u) << 16; return v.f;
}
__device__ __forceinline__ u16 f2bf(float f) {
  union { float f; unsigned int i; } v; v.f = f;
  unsigned int x = v.i;
  return (u16)((x + 0x7fffu + ((x >> 16) & 1u)) >> 16);   // RNE
}
__device__ __forceinline__ float siluf_(float v) {
  return v / (1.0f + __expf(-v));
}
__device__ __forceinline__ float softplusf_(float v) {
  return fmaxf(v, 0.0f) + log1pf(__expf(-fabsf(v)));
}
__device__ __forceinline__ void gload16(const void* g, void* l) {
  __builtin_amdgcn_global_load_lds((const __attribute__((address_space(1))) void*)g,
                                   (__attribute__((address_space(3))) void*)l,
                                   16, 0, 0);
}

// ---------------- fp32 -> bf16 convert ----------------
__global__ void to_bf16(const float* __restrict__ in, u16* __restrict__ out, int n4) {
  int i = blockIdx.x * blockDim.x + threadIdx.x;
  if (i >= n4) return;
  float4 v = ((const float4*)in)[i];
  u16x4 o;
  o.x = f2bf(v.x); o.y = f2bf(v.y); o.z = f2bf(v.z); o.w = f2bf(v.w);
  ((u16x4*)out)[i] = o;
}

// ---------------- bf16 MFMA GEMM, C = A(MxK) * Bt(NxK)^T ----------------
// Round-0 m97 structure (proven 557 TF on in_proj) + three validated deltas:
//  * BK=64 (was 32): halves __syncthreads drain events per K-loop.
//  * T2 both-sides LDS swizzle (validated r1/r2: conflicts 9.4M -> 0, refpassed):
//    global_load_lds writes linearly; SOURCE col chunk pre-XOR'd by (row&7),
//    reads XOR the same involution -> conflict-free at 128 B row stride.
//  * T1 bijective XCD block swizzle (all grids are multiples of 8 WGs).
// 128x128 tile, 4 waves 2x2, per-wave 64x64 (4x4 of 16x16), single-buffer LDS,
// stage -> sync -> (kb=0,1: ds_read frags + 16 MFMA) -> sync. K accumulation
// order identical to round 0 (bitwise-same numerics).
//
// EPI 0: plain fp32 C store (c_out, ld N)
// EPI 1: in_proj: col<DI -> bf16 x_inner e_bf_a; col>=DI -> silu -> bf16 e_bf1
// EPI 2: dt: dt=softplus(acc+e_v2[col]); a=exp(e_v1[col]*dt);
//        w = bf2f(e_bf2[row,col])*dt*a -> e_bf_a ; a -> e_bf1
template <int EPI>
__launch_bounds__(256, 3)
__global__ void gemm_bt(const u16* __restrict__ A, const u16* __restrict__ Bt,
                        float* __restrict__ c_out,
                        int N, int K,
                        u16* __restrict__ e_bf_a,
                        u16* __restrict__ e_bf1,
                        const u16* __restrict__ e_bf2,
                        const float* __restrict__ e_v1,
                        const float* __restrict__ e_v2) {
  __shared__ u16 Alds[128 * 64];   // 16 KB
  __shared__ u16 Blds[128 * 64];   // 16 KB

  const int tid  = threadIdx.x;
  const int wave = tid >> 6;
  const int lane = tid & 63;
  const int quad = lane >> 4;
  const int l16  = lane & 15;

  // bijective XCD-aware block swizzle (nwg % 8 == 0 for every grid used here)
  const int nwg  = (int)(gridDim.x * gridDim.y);
  const int orig = (int)(blockIdx.y * gridDim.x + blockIdx.x);
  const int swz  = (orig & 7) * (nwg >> 3) + (orig >> 3);
  const int bx   = swz % (int)gridDim.x;
  const int by   = swz / (int)gridDim.x;
  const int m0 = by * 128;
  const int n0 = bx * 128;

  const int waveM = wave & 1;      // 2x2 wave grid
  const int waveN = wave >> 1;

  // staging: tile = 128 rows x 128 B = 1024 chunks of 16B; thread covers 4 chunks
  // per matrix: row = r*32 + (tid>>3), chunk q = tid&7, source col pre-swizzled
  // by (row&7) so the linear DMA lands the swizzled layout (r*32 keeps row&7).
  const int srow = tid >> 3;                       // 0..31
  const int scol = ((tid & 7) ^ (srow & 7)) * 8;   // pre-swizzled source col (elems)
  const u16* Ap = A  + (size_t)(m0 + srow) * K + scol;
  const u16* Bp = Bt + (size_t)(n0 + srow) * K + scol;
  u16* adst = &Alds[tid * 8];
  u16* bdst = &Blds[tid * 8];

  const unsigned xorc = (unsigned)(l16 & 7) << 3;  // read-side involution (elems)

  f32x4 acc[4][4] = {};

  for (int k0 = 0; k0 < K; k0 += 64) {
#pragma unroll
    for (int r = 0; r < 4; ++r) {
      gload16(Ap + (size_t)(r * 32) * K + k0, adst + r * 2048);
      gload16(Bp + (size_t)(r * 32) * K + k0, bdst + r * 2048);
    }
    __syncthreads();

#pragma unroll
    for (int kb = 0; kb < 2; ++kb) {
      short8 af[4], bf[4];
      const unsigned ck = (unsigned)(kb * 32 + quad * 8) ^ xorc;
#pragma unroll
      for (int i = 0; i < 4; i++) {
        af[i] = *(const short8*)&Alds[(unsigned)(waveM * 64 + i * 16 + l16) * 64 + ck];
        bf[i] = *(const short8*)&Blds[(unsigned)(waveN * 64 + i * 16 + l16) * 64 + ck];
      }
#pragma unroll
      for (int mi = 0; mi < 4; mi++)
#pragma unroll
        for (int ni = 0; ni < 4; ni++)
          acc[mi][ni] = __builtin_amdgcn_mfma_f32_16x16x32_bf16(af[mi], bf[ni],
                                                                acc[mi][ni], 0, 0, 0);
    }
    __syncthreads();
  }

  // epilogue: C/D layout col=lane&15, row=quad*4+reg (m89/m91-verified)
#pragma unroll
  for (int mi = 0; mi < 4; mi++) {
    const int rowBase = m0 + waveM * 64 + mi * 16 + quad * 4;
#pragma unroll
    for (int ni = 0; ni < 4; ni++) {
      const int gcol = n0 + waveN * 64 + ni * 16 + l16;
#pragma unroll
      for (int r = 0; r < 4; r++) {
        const float v = acc[mi][ni][r];
        const size_t row = (size_t)(rowBase + r);
        if constexpr (EPI == 0) {
          c_out[row * (size_t)N + gcol] = v;
        } else if constexpr (EPI == 1) {
          if (gcol < DI) {
            e_bf_a[row * DI + gcol] = f2bf(v);
          } else {
            e_bf1[row * DI + (gcol - DI)] = f2bf(siluf_(v));
          }
        } else {
          const float dt = softplusf_(v + e_v2[gcol]);
          const float a  = __expf(e_v1[gcol] * dt);
          const float xc = bf2f(e_bf2[row * DI + gcol]);
          e_bf_a[row * DI + gcol] = f2bf(xc * dt * a);
          e_bf1[row * DI + gcol] = f2bf(a);
        }
      }
    }
  }
}

// ---------------- depthwise conv1d(k=3,pad=1) + bias + SiLU ----------------------
// works for any row count; batch boundary via l = row & (L_SEQ-1)
__global__ void conv_silu(const u16* __restrict__ xin, const float* __restrict__ cw,
                          const float* __restrict__ cb, u16* __restrict__ xconv_bf) {
  const int idx = blockIdx.x * blockDim.x + threadIdx.x;   // one thread = 4 channels
  const int c4  = (idx % (DI / 4)) * 4;
  const int row = idx / (DI / 4);
  const int l   = row & (L_SEQ - 1);

  const size_t base = (size_t)row * DI + c4;
  u16x4 z4 = {0, 0, 0, 0};
  u16x4 x1 = *(const u16x4*)(xin + base);
  u16x4 x0 = (l > 0)         ? *(const u16x4*)(xin + base - DI) : z4;
  u16x4 x2 = (l < L_SEQ - 1) ? *(const u16x4*)(xin + base + DI) : z4;

  const u16* p0 = (const u16*)&x0;
  const u16* p1 = (const u16*)&x1;
  const u16* p2 = (const u16*)&x2;
  u16x4 o;
  u16* po = (u16*)&o;
#pragma unroll
  for (int j = 0; j < 4; j++) {
    const int c = c4 + j;
    float v = fmaf(cw[c * 3 + 0], bf2f(p0[j]),
              fmaf(cw[c * 3 + 1], bf2f(p1[j]),
                   cw[c * 3 + 2] * bf2f(p2[j]))) + cb[c];
    po[j] = f2bf(siluf_(v));
  }
  *(u16x4*)&xconv_bf[base] = o;
}

// ---------------- chunked prefix scan over L (chunk=128, 32 chunks/batch) --------
#define CHUNK 128
#define NCHUNK (L_SEQ / CHUNK)   // 32

__global__ void scan_partial(const u16* __restrict__ w, float* __restrict__ partial) {
  const int c  = blockIdx.x * 256 + threadIdx.x;   // 0..1535
  const int ch = blockIdx.y;
  const int b  = blockIdx.z;
  size_t base = ((size_t)b * L_SEQ + (size_t)ch * CHUNK) * DI + c;
  float s = 0.0f;
#pragma unroll 4
  for (int i = 0; i < CHUNK; i++) s += bf2f(w[base + (size_t)i * DI]);
  partial[((size_t)b * NCHUNK + ch) * DI + c] = s;
}

__global__ void scan_offsets(float* __restrict__ partial) {
  const int c = blockIdx.x * 256 + threadIdx.x;    // 0..1535
  const int b = blockIdx.z;
  float run = 0.0f;
  for (int ch = 0; ch < NCHUNK; ch++) {
    size_t p = ((size_t)b * NCHUNK + ch) * DI + c;
    float v = partial[p];
    partial[p] = run;
    run += v;
  }
}

// NOTE: ybf aliases aexp (same index read-then-write per thread) — no __restrict__.
__global__ void scan_apply(const u16* __restrict__ w, const float* __restrict__ partial,
                           const u16* aexp, const u16* __restrict__ xconv,
                           const u16* __restrict__ sz, const float* __restrict__ Dp,
                           u16* ybf) {
  const int c  = blockIdx.x * 256 + threadIdx.x;
  const int ch = blockIdx.y;
  const int b  = blockIdx.z;
  float run = partial[((size_t)b * NCHUNK + ch) * DI + c];
  const float dp = Dp[c];
  size_t base = ((size_t)b * L_SEQ + (size_t)ch * CHUNK) * DI + c;
  for (int i = 0; i < CHUNK; i++) {
    size_t p = base + (size_t)i * DI;
    float ae = bf2f(aexp[p]);             // read BEFORE the aliased write
    run += bf2f(w[p]);
    float y = run * ae + bf2f(xconv[p]) * dp;
    y *= bf2f(sz[p]);
    ybf[p] = f2bf(y);
  }
}

// ---------------- launcher ----------------
extern "C" void kernel_launch(void* const* d_in, const int* in_sizes, int n_in,
                              void* d_out, int out_size, void* d_ws, size_t ws_size,
                              hipStream_t stream) {
  const float* x      = (const float*)d_in[0];
  const float* W_in   = (const float*)d_in[1];   // (3072,1024)
  const float* W_out  = (const float*)d_in[2];   // (1024,1536)
  const float* conv_w = (const float*)d_in[3];   // (1536,1,3)
  const float* conv_b = (const float*)d_in[4];
  const float* dt_w   = (const float*)d_in[5];   // (1536,1536)
  const float* dt_b   = (const float*)d_in[6];
  const float* Avec   = (const float*)d_in[7];
  const float* Dp     = (const float*)d_in[8];
  float* out = (float*)d_out;
  char* ws = (char*)d_ws;

  // weights -> bf16 (shared by both paths; layout prefix identical)
  u16* Win_bf  = (u16*)(ws + 0);          //  6,291,456
  u16* dtw_bf  = (u16*)(ws + 6291456);    //  4,718,592
  u16* Wout_bf = (u16*)(ws + 11010048);   //  3,145,728  -> end 14,155,776
  to_bf16<<<3072, 256, 0, stream>>>(W_in,  Win_bf,  786432);
  to_bf16<<<2304, 256, 0, stream>>>(dt_w,  dtw_bf,  589824);
  to_bf16<<<1536, 256, 0, stream>>>(W_out, Wout_bf, 393216);

  const size_t FULL_NEED = 249823232;   // full-batch layout
  if (ws_size >= FULL_NEED) {
    // ---------- full-batch path: M = 16384 ----------
    u16*   x_bf     = (u16*)  (ws + 14155776);    // 33,554,432  (16384x1024)
    u16*   xin_bf   = (u16*)  (ws + 47710208);    // 50,331,648  [w aliases]
    u16*   sz_bf    = (u16*)  (ws + 98041856);    // 50,331,648
    u16*   xconv_bf = (u16*)  (ws + 148373504);   // 50,331,648
    u16*   aexp_bf  = (u16*)  (ws + 198705152);   // 50,331,648  [y aliases]
    float* part     = (float*)(ws + 249036800);   //    786,432  (4x32x1536)
    u16*   w_bf     = xin_bf;
    u16*   y_bf     = aexp_bf;

    to_bf16<<<16384, 256, 0, stream>>>(x, x_bf, 4194304);

    // in_proj GEMM (M=16384, N=3072, K=1024) + split epilogue
    gemm_bt<1><<<dim3(24, 128), 256, 0, stream>>>(x_bf, Win_bf, nullptr,
                                                  2 * DI, DIM_IN,
                                                  xin_bf, sz_bf, nullptr, nullptr, nullptr);
    // depthwise conv + SiLU (batch edges via l = row & 4095)
    conv_silu<<<24576, 256, 0, stream>>>(xin_bf, conv_w, conv_b, xconv_bf);

    // dt GEMM (M=16384, N=1536, K=1536) + softplus/exp/w epilogue
    gemm_bt<2><<<dim3(12, 128), 256, 0, stream>>>(xconv_bf, dtw_bf, nullptr,
                                                  DI, DI,
                                                  w_bf, aexp_bf, xconv_bf, Avec, dt_b);

    // chunked prefix scan + pointwise tail
    scan_partial<<<dim3(6, NCHUNK, BATCH), 256, 0, stream>>>(w_bf, part);
    scan_offsets<<<dim3(6, 1, BATCH), 256, 0, stream>>>(part);
    scan_apply<<<dim3(6, NCHUNK, BATCH), 256, 0, stream>>>(w_bf, part, aexp_bf,
                                                           xconv_bf, sz_bf, Dp, y_bf);

    // out_proj GEMM (M=16384, N=1024, K=1536) -> fp32 output
    gemm_bt<0><<<dim3(8, 128), 256, 0, stream>>>(y_bf, Wout_bf, out,
                                                 DIM_IN, DI,
                                                 nullptr, nullptr, nullptr, nullptr, nullptr);
    return;
  }

  // ---------- per-batch fallback (73 MB), M = 4096 ----------
  const size_t WS_NEED = 73072640;
  if (ws_size < WS_NEED) return;   // diagnostic: absmax=2096 w/o crash => ws too small

  u16*   x_bf     = (u16*)  (ws + 14155776);   //  8,388,608   (4096x1024)
  u16*   xin_bf   = (u16*)  (ws + 22544384);   // 12,582,912   [w aliases]
  u16*   sz_bf    = (u16*)  (ws + 35127296);   // 12,582,912
  u16*   xconv_bf = (u16*)  (ws + 47710208);   // 12,582,912
  u16*   aexp_bf  = (u16*)  (ws + 60293120);   // 12,582,912   [y aliases]
  float* part     = (float*)(ws + 72876032);   //    196,608
  u16*   w_bf     = xin_bf;
  u16*   y_bf     = aexp_bf;

  for (int b = 0; b < BATCH; b++) {
    const float* xb   = x   + (size_t)b * L_SEQ * DIM_IN;
    float*       outb = out + (size_t)b * L_SEQ * DIM_IN;

    to_bf16<<<4096, 256, 0, stream>>>(xb, x_bf, 1048576);
    gemm_bt<1><<<dim3(24, 32), 256, 0, stream>>>(x_bf, Win_bf, nullptr,
                                                 2 * DI, DIM_IN,
                                                 xin_bf, sz_bf, nullptr, nullptr, nullptr);
    conv_silu<<<6144, 256, 0, stream>>>(xin_bf, conv_w, conv_b, xconv_bf);
    gemm_bt<2><<<dim3(12, 32), 256, 0, stream>>>(xconv_bf, dtw_bf, nullptr,
                                                 DI, DI,
                                                 w_bf, aexp_bf, xconv_bf, Avec, dt_b);
    scan_partial<<<dim3(6, NCHUNK, 1), 256, 0, stream>>>(w_bf, part);
    scan_offsets<<<dim3(6, 1, 1), 256, 0, stream>>>(part);
    scan_apply<<<dim3(6, NCHUNK, 1), 256, 0, stream>>>(w_bf, part, aexp_bf,
                                                       xconv_bf, sz_bf, Dp, y_bf);
    gemm_bt<0><<<dim3(8, 32), 256, 0, stream>>>(y_bf, Wout_bf, outb,
                                                DIM_IN, DI,
                                                nullptr, nullptr, nullptr, nullptr, nullptr);
  }
}